// Round 18
// baseline (492.604 us; speedup 1.0000x reference)
//
#include <hip/hip_runtime.h>

typedef __bf16 bf16;
typedef __bf16 bf16x8 __attribute__((ext_vector_type(8)));
typedef float f32x4 __attribute__((ext_vector_type(4)));

#define S_NB 50

// ---------------- weight pre-shuffle: f32 -> bf16 MFMA B-fragment layout ----
__global__ __launch_bounds__(256) void shuffle_w(const float* __restrict__ gatW,
                                                 bf16* __restrict__ ws) {
  int tid = blockIdx.x * 256 + threadIdx.x;
  if (tid >= 6 * 512) return;
  int mat = tid >> 9;
  int rem = tid & 511;
  int ks = rem >> 8;
  int nt = (rem >> 6) & 3;
  int lane = rem & 63;
  int t = mat >> 1, p = (mat & 1) + 1;
  const float* src = gatW + (size_t)(t * 4 + p) * 4096;
  int n = nt * 16 + (lane & 15);
  int kb = ks * 32 + (lane >> 4) * 8;
  bf16x8 v;
#pragma unroll
  for (int e = 0; e < 8; ++e) v[e] = (bf16)src[(kb + e) * 64 + n];
  *reinterpret_cast<bf16x8*>(ws + mat * 4096 + ((ks * 4 + nt) * 64 + lane) * 8) = v;
}

// inst mapping: 0:U(u_movies,item | node user[uids])  1:M(m_querys,query | item[mids])
//               2:M(m_users,user | item[mids])        3:Q(q_movies,item | query[qids])

// ---- gat_all2: ILP-2 — one wave per ib-PAIR (2w, 2w+1), shared weights. ----
__global__ __launch_bounds__(256) void gat_all2(
    const int* __restrict__ uids, const int* __restrict__ qids,
    const int* __restrict__ mids, const int* __restrict__ u_movies,
    const int* __restrict__ m_querys, const int* __restrict__ m_users,
    const int* __restrict__ q_movies, const float* __restrict__ user_t,
    const float* __restrict__ item_t, const float* __restrict__ query_t,
    const float* __restrict__ gatW, const float* __restrict__ gatB,
    const bf16* __restrict__ wfrag, float* __restrict__ agg, int B) {
  int w = (blockIdx.x * 256 + threadIdx.x) >> 6;
  int lane = threadIdx.x & 63;
  int ib0 = 2 * w;            // B even -> ib0, ib0+1 share inst
  int inst = ib0 / B;
  int b0 = ib0 - inst * B;
  int c15 = lane & 15, g = lane >> 4;

  const int* idx; const float* nbt; const float* ndt; int woff;
  int nid[2];
  if (inst == 0) { idx = u_movies; nbt = item_t; ndt = user_t; woff = 0;
    nid[0] = uids[b0]; nid[1] = uids[b0 + 1]; }
  else if (inst == 1) { idx = m_querys; nbt = query_t; ndt = item_t; woff = 1;
    nid[0] = mids[b0]; nid[1] = mids[b0 + 1]; }
  else if (inst == 2) { idx = m_users; nbt = user_t; ndt = item_t; woff = 1;
    nid[0] = mids[b0]; nid[1] = mids[b0 + 1]; }
  else { idx = q_movies; nbt = item_t; ndt = query_t; woff = 2;
    nid[0] = qids[b0]; nid[1] = qids[b0 + 1]; }
  const float* Wt = gatW + (size_t)woff * 4 * 4096;
  const float* bt = gatB + woff * 256;
  const bf16* frk = wfrag + woff * 8192;
  const bf16* frv = wfrag + woff * 8192 + 4096;

  // node rows + A fragments for both batches (independent gather streams)
  float nd[2];
  bf16x8 af0[2][4], af1[2][4];
#pragma unroll
  for (int j = 0; j < 2; ++j) {
    nd[j] = ndt[(size_t)nid[j] * 64 + lane];
#pragma unroll
    for (int m = 0; m < 4; ++m) {
      int arow = m * 16 + c15;
      int id = (arow < S_NB) ? idx[(b0 + j) * S_NB + arow] : 0;
      const float* rowp = nbt + (size_t)id * 64;
      float4 f0 = *reinterpret_cast<const float4*>(rowp + g * 8);
      float4 f1 = *reinterpret_cast<const float4*>(rowp + g * 8 + 4);
      float4 f2 = *reinterpret_cast<const float4*>(rowp + 32 + g * 8);
      float4 f3 = *reinterpret_cast<const float4*>(rowp + 32 + g * 8 + 4);
      af0[j][m][0] = (bf16)f0.x; af0[j][m][1] = (bf16)f0.y;
      af0[j][m][2] = (bf16)f0.z; af0[j][m][3] = (bf16)f0.w;
      af0[j][m][4] = (bf16)f1.x; af0[j][m][5] = (bf16)f1.y;
      af0[j][m][6] = (bf16)f1.z; af0[j][m][7] = (bf16)f1.w;
      af1[j][m][0] = (bf16)f2.x; af1[j][m][1] = (bf16)f2.y;
      af1[j][m][2] = (bf16)f2.z; af1[j][m][3] = (bf16)f2.w;
      af1[j][m][4] = (bf16)f3.x; af1[j][m][5] = (bf16)f3.y;
      af1[j][m][6] = (bf16)f3.z; af1[j][m][7] = (bf16)f3.w;
    }
  }

  // qp for both batches; weight load shared (same 4-acc order per batch)
  float qv[2];
  {
    float q0[2] = {0.f, 0.f}, q1[2] = {0.f, 0.f};
    float q2[2] = {0.f, 0.f}, q3[2] = {0.f, 0.f};
#pragma unroll 4
    for (int k = 0; k < 64; k += 4) {
      float w0 = Wt[k * 64 + lane];
      float w1 = Wt[(k + 1) * 64 + lane];
      float w2 = Wt[(k + 2) * 64 + lane];
      float w3 = Wt[(k + 3) * 64 + lane];
#pragma unroll
      for (int j = 0; j < 2; ++j) {
        q0[j] += __shfl(nd[j], k, 64) * w0;
        q1[j] += __shfl(nd[j], k + 1, 64) * w1;
        q2[j] += __shfl(nd[j], k + 2, 64) * w2;
        q3[j] += __shfl(nd[j], k + 3, 64) * w3;
      }
    }
    float bb = bt[lane];
#pragma unroll
    for (int j = 0; j < 2; ++j)
      qv[j] = fmaxf((((q0[j] + q1[j]) + q2[j]) + q3[j]) + bb, 0.f);
  }

  // K phase: scores; B-fragments loaded once for both batches
  float s[2][4][4];
#pragma unroll
  for (int j = 0; j < 2; ++j)
#pragma unroll
    for (int m = 0; m < 4; ++m)
#pragma unroll
      for (int e = 0; e < 4; ++e) s[j][m][e] = 0.f;
#pragma unroll
  for (int nt = 0; nt < 4; ++nt) {
    bf16x8 bk0 = *reinterpret_cast<const bf16x8*>(frk + ((0 * 4 + nt) * 64 + lane) * 8);
    bf16x8 bk1 = *reinterpret_cast<const bf16x8*>(frk + ((1 * 4 + nt) * 64 + lane) * 8);
    float kb = bt[64 + nt * 16 + c15];
#pragma unroll
    for (int j = 0; j < 2; ++j) {
      float qpv = __shfl(qv[j], nt * 16 + c15, 64);
#pragma unroll
      for (int m = 0; m < 4; ++m) {
        f32x4 acc = {0.f, 0.f, 0.f, 0.f};
        acc = __builtin_amdgcn_mfma_f32_16x16x32_bf16(af0[j][m], bk0, acc, 0, 0, 0);
        acc = __builtin_amdgcn_mfma_f32_16x16x32_bf16(af1[j][m], bk1, acc, 0, 0, 0);
#pragma unroll
        for (int e = 0; e < 4; ++e) s[j][m][e] += fmaxf(acc[e] + kb, 0.f) * qpv;
      }
    }
  }
#pragma unroll
  for (int msk = 1; msk < 16; msk <<= 1)
#pragma unroll
    for (int j = 0; j < 2; ++j)
#pragma unroll
      for (int m = 0; m < 4; ++m)
#pragma unroll
        for (int e = 0; e < 4; ++e) s[j][m][e] += __shfl_xor(s[j][m][e], msk, 64);

  // transpose to per-lane scores, softmax (two independent chains)
  int m_l = lane >> 4, e_l = lane & 3, gg = (lane & 15) >> 2;
  float pvn[2];
#pragma unroll
  for (int j = 0; j < 2; ++j) {
    float sv = -1e30f;
#pragma unroll
    for (int m = 0; m < 4; ++m)
#pragma unroll
      for (int e = 0; e < 4; ++e) {
        float v = __shfl(s[j][m][e], gg * 16, 64);
        sv = (m_l == m && e_l == e) ? v : sv;
      }
    float svm = (lane < S_NB) ? sv : -1e30f;
    float mx = svm;
#pragma unroll
    for (int msk = 1; msk < 64; msk <<= 1) mx = fmaxf(mx, __shfl_xor(mx, msk, 64));
    float ev = (lane < S_NB) ? __expf((svm - mx) * 0.125f) : 0.f;
    float den = ev;
#pragma unroll
    for (int msk = 1; msk < 64; msk <<= 1) den += __shfl_xor(den, msk, 64);
    pvn[j] = ev / den;
  }

  // prob weights
  float pwv[2][4][4];
#pragma unroll
  for (int j = 0; j < 2; ++j)
#pragma unroll
    for (int m = 0; m < 4; ++m)
#pragma unroll
      for (int e = 0; e < 4; ++e)
        pwv[j][m][e] = __shfl(pvn[j], m * 16 + g * 4 + e, 64);

  // V phase: PV accumulate; V-fragments loaded once
  float yacc[2][4];
#pragma unroll
  for (int j = 0; j < 2; ++j)
#pragma unroll
    for (int nt = 0; nt < 4; ++nt) yacc[j][nt] = 0.f;
#pragma unroll
  for (int nt = 0; nt < 4; ++nt) {
    bf16x8 bv0 = *reinterpret_cast<const bf16x8*>(frv + ((0 * 4 + nt) * 64 + lane) * 8);
    bf16x8 bv1 = *reinterpret_cast<const bf16x8*>(frv + ((1 * 4 + nt) * 64 + lane) * 8);
    float vb = bt[128 + nt * 16 + c15];
#pragma unroll
    for (int j = 0; j < 2; ++j) {
#pragma unroll
      for (int m = 0; m < 4; ++m) {
        f32x4 acc = {0.f, 0.f, 0.f, 0.f};
        acc = __builtin_amdgcn_mfma_f32_16x16x32_bf16(af0[j][m], bv0, acc, 0, 0, 0);
        acc = __builtin_amdgcn_mfma_f32_16x16x32_bf16(af1[j][m], bv1, acc, 0, 0, 0);
        yacc[j][nt] += pwv[j][m][0] * fmaxf(acc[0] + vb, 0.f) +
                       pwv[j][m][1] * fmaxf(acc[1] + vb, 0.f) +
                       pwv[j][m][2] * fmaxf(acc[2] + vb, 0.f) +
                       pwv[j][m][3] * fmaxf(acc[3] + vb, 0.f);
      }
    }
  }
#pragma unroll
  for (int j = 0; j < 2; ++j)
#pragma unroll
    for (int nt = 0; nt < 4; ++nt) {
      yacc[j][nt] += __shfl_xor(yacc[j][nt], 16, 64);
      yacc[j][nt] += __shfl_xor(yacc[j][nt], 32, 64);
    }

  // agg for both batches; W3 load shared (same 4-acc order per batch)
  {
    const float* W3 = Wt + 3 * 4096;
    float a0[2] = {0.f, 0.f}, a1[2] = {0.f, 0.f};
    float a2[2] = {0.f, 0.f}, a3[2] = {0.f, 0.f};
#pragma unroll
    for (int k = 0; k < 64; k += 4) {
      float w0 = W3[(k + 0) * 64 + lane];
      float w1 = W3[(k + 1) * 64 + lane];
      float w2 = W3[(k + 2) * 64 + lane];
      float w3 = W3[(k + 3) * 64 + lane];
#pragma unroll
      for (int j = 0; j < 2; ++j) {
        a0[j] += __shfl(yacc[j][(k + 0) >> 4], (k + 0) & 15, 64) * w0;
        a1[j] += __shfl(yacc[j][(k + 1) >> 4], (k + 1) & 15, 64) * w1;
        a2[j] += __shfl(yacc[j][(k + 2) >> 4], (k + 2) & 15, 64) * w2;
        a3[j] += __shfl(yacc[j][(k + 3) >> 4], (k + 3) & 15, 64) * w3;
      }
    }
    float bb = gatB[woff * 256 + 192 + lane];
#pragma unroll
    for (int j = 0; j < 2; ++j)
      agg[(size_t)(ib0 + j) * 64 + lane] =
          fmaxf((((a0[j] + a1[j]) + a2[j]) + a3[j]) + bb, 0.f);
  }
}

// ---- k_sem2: ILP-2 — one wave per (tower, b-pair), shared weights. ---------
__global__ __launch_bounds__(256) void k_sem2(
    const int* __restrict__ uids, const int* __restrict__ qids,
    const int* __restrict__ mids, const float* __restrict__ user_t,
    const float* __restrict__ item_t, const float* __restrict__ query_t,
    const float* __restrict__ semW, const float* __restrict__ semB,
    const float* __restrict__ agg, float* __restrict__ out, int B) {
  int w = (blockIdx.x * 256 + threadIdx.x) >> 6;
  int lane = threadIdx.x & 63;
  int B2 = B >> 1;
  int t = w / B2;
  int b0 = (w - t * B2) * 2;

  float nd[2], k1v[2], k2v[2];
  int ns;
  if (t == 0) {
#pragma unroll
    for (int j = 0; j < 2; ++j) {
      nd[j] = user_t[(size_t)uids[b0 + j] * 64 + lane];
      k1v[j] = agg[(size_t)(0 * B + b0 + j) * 64 + lane];
      k2v[j] = k1v[j];
    }
    ns = 2;
  } else if (t == 1) {
#pragma unroll
    for (int j = 0; j < 2; ++j) {
      nd[j] = item_t[(size_t)mids[b0 + j] * 64 + lane];
      k1v[j] = agg[(size_t)(1 * B + b0 + j) * 64 + lane];
      k2v[j] = agg[(size_t)(2 * B + b0 + j) * 64 + lane];
    }
    ns = 3;
  } else {
#pragma unroll
    for (int j = 0; j < 2; ++j) {
      nd[j] = query_t[(size_t)qids[b0 + j] * 64 + lane];
      k1v[j] = agg[(size_t)(3 * B + b0 + j) * 64 + lane];
      k2v[j] = k1v[j];
    }
    ns = 2;
  }
  const float* Ws = semW + (size_t)t * 4 * 4096;
  const float* bs = semB + t * 256;

  // qs = relu(node @ W0 + b0); weight loads shared
  float qs[2];
  {
    float q0[2] = {0.f, 0.f}, q1[2] = {0.f, 0.f};
#pragma unroll 4
    for (int k = 0; k < 64; k += 2) {
      float w0 = Ws[k * 64 + lane];
      float w1 = Ws[(k + 1) * 64 + lane];
#pragma unroll
      for (int j = 0; j < 2; ++j) {
        q0[j] += __shfl(nd[j], k, 64) * w0;
        q1[j] += __shfl(nd[j], k + 1, 64) * w1;
      }
    }
    float bb = bs[lane];
#pragma unroll
    for (int j = 0; j < 2; ++j) qs[j] = fmaxf(q0[j] + q1[j] + bb, 0.f);
  }

  // kp/vp rows; W1/W2 loads shared
  const float* W1 = Ws + 4096;
  const float* W2 = Ws + 2 * 4096;
  float kp0[2] = {0.f, 0.f}, kp1[2] = {0.f, 0.f}, kp2[2] = {0.f, 0.f};
  float vp0[2] = {0.f, 0.f}, vp1[2] = {0.f, 0.f}, vp2[2] = {0.f, 0.f};
#pragma unroll 2
  for (int k = 0; k < 64; ++k) {
    float w1 = W1[k * 64 + lane];
    float w2 = W2[k * 64 + lane];
#pragma unroll
    for (int j = 0; j < 2; ++j) {
      float nk = __shfl(nd[j], k, 64);
      float a1k = __shfl(k1v[j], k, 64);
      float a2k = __shfl(k2v[j], k, 64);
      kp0[j] += nk * w1; kp1[j] += a1k * w1; kp2[j] += a2k * w1;
      vp0[j] += nk * w2; vp1[j] += a1k * w2; vp2[j] += a2k * w2;
    }
  }
  float bk = bs[64 + lane], bv = bs[128 + lane];
  float yv[2];
#pragma unroll
  for (int j = 0; j < 2; ++j) {
    float k0 = fmaxf(kp0[j] + bk, 0.f);
    float k1 = fmaxf(kp1[j] + bk, 0.f);
    float k2 = fmaxf(kp2[j] + bk, 0.f);
    float v0 = fmaxf(vp0[j] + bv, 0.f);
    float v1 = fmaxf(vp1[j] + bv, 0.f);
    float v2 = fmaxf(vp2[j] + bv, 0.f);
    float s0 = qs[j] * k0, s1 = qs[j] * k1, s2 = qs[j] * k2;
#pragma unroll
    for (int msk = 1; msk < 64; msk <<= 1) {
      s0 += __shfl_xor(s0, msk, 64);
      s1 += __shfl_xor(s1, msk, 64);
      s2 += __shfl_xor(s2, msk, 64);
    }
    s0 *= 0.125f; s1 *= 0.125f; s2 *= 0.125f;
    float mx = fmaxf(s0, s1);
    if (ns > 2) mx = fmaxf(mx, s2);
    float e0 = __expf(s0 - mx);
    float e1 = __expf(s1 - mx);
    float e2 = (ns > 2) ? __expf(s2 - mx) : 0.f;
    float rd = 1.f / (e0 + e1 + e2);
    yv[j] = (e0 * v0 + e1 * v1 + e2 * v2) * rd;
  }

  // out = relu(y @ W3 + b3); W3 loads shared
  {
    const float* W3 = Ws + 3 * 4096;
    float o0[2] = {0.f, 0.f}, o1[2] = {0.f, 0.f};
#pragma unroll 4
    for (int k = 0; k < 64; k += 2) {
      float w0 = W3[k * 64 + lane];
      float w1 = W3[(k + 1) * 64 + lane];
#pragma unroll
      for (int j = 0; j < 2; ++j) {
        o0[j] += __shfl(yv[j], k, 64) * w0;
        o1[j] += __shfl(yv[j], k + 1, 64) * w1;
      }
    }
    float bb = bs[192 + lane];
#pragma unroll
    for (int j = 0; j < 2; ++j)
      out[(size_t)(b0 + j) * 192 + t * 64 + lane] = fmaxf(o0[j] + o1[j] + bb, 0.f);
  }
}

extern "C" void kernel_launch(void* const* d_in, const int* in_sizes, int n_in,
                              void* d_out, int out_size, void* d_ws, size_t ws_size,
                              hipStream_t stream) {
  const int* uids = (const int*)d_in[0];
  const int* qids = (const int*)d_in[1];
  const int* mids = (const int*)d_in[2];
  const int* u_movies = (const int*)d_in[3];
  const int* m_querys = (const int*)d_in[4];
  const int* m_users = (const int*)d_in[5];
  const int* q_movies = (const int*)d_in[6];
  const float* user_t = (const float*)d_in[7];
  const float* item_t = (const float*)d_in[8];
  const float* query_t = (const float*)d_in[9];
  const float* gatW = (const float*)d_in[10];
  const float* gatB = (const float*)d_in[11];
  const float* semW = (const float*)d_in[12];
  const float* semB = (const float*)d_in[13];
  float* out = (float*)d_out;

  int B = in_sizes[0];
  bf16* wfrag = (bf16*)d_ws;
  float* wsf = (float*)d_ws;
  float* agg = wsf + 16384;  // 4*B*64 floats

  shuffle_w<<<12, 256, 0, stream>>>(gatW, wfrag);
  // gat_all2: 4*B/2 waves, 4 waves/block
  gat_all2<<<B / 2, 256, 0, stream>>>(uids, qids, mids, u_movies, m_querys,
                                      m_users, q_movies, user_t, item_t,
                                      query_t, gatW, gatB, wfrag, agg, B);
  // k_sem2: 3*B/2 waves, 4 waves/block
  k_sem2<<<3 * B / 8, 256, 0, stream>>>(uids, qids, mids, user_t, item_t,
                                        query_t, semW, semB, agg, out, B);
}